// Round 1
// baseline (200.833 us; speedup 1.0000x reference)
//
#include <hip/hip_runtime.h>
#include <stdint.h>

typedef __attribute__((ext_vector_type(8))) short bf8v;   // 8 bf16 raw bits (4 VGPRs)
typedef __attribute__((ext_vector_type(4))) float f4v;

__device__ __forceinline__ unsigned short f2bf(float f) {
  unsigned int u = __float_as_uint(f);
  u += 0x7fffu + ((u >> 16) & 1u);   // round-to-nearest-even
  return (unsigned short)(u >> 16);
}

__device__ __forceinline__ void gload16(const void* g, void* l) {
  __builtin_amdgcn_global_load_lds(
      (__attribute__((address_space(1))) void*)reinterpret_cast<uintptr_t>(g),
      (__attribute__((address_space(3))) void*)reinterpret_cast<uintptr_t>(l),
      16, 0, 0);
}

// ---------------- fp32 -> bf16 conversion (vectorized, G13) ----------------
__global__ __launch_bounds__(256) void cvt_many(
    const float* __restrict__ s0, const float* __restrict__ s1,
    const float* __restrict__ s2, const float* __restrict__ s3,
    unsigned short* __restrict__ d0, unsigned short* __restrict__ d1,
    unsigned short* __restrict__ d2, unsigned short* __restrict__ d3, int n) {
  int a = blockIdx.y;
  const float* src = (a == 0) ? s0 : (a == 1) ? s1 : (a == 2) ? s2 : s3;
  unsigned short* dst = (a == 0) ? d0 : (a == 1) ? d1 : (a == 2) ? d2 : d3;
  int i = (blockIdx.x * 256 + threadIdx.x) * 8;
  if (i >= n) return;
  const f4v* sp = (const f4v*)(src + i);
  f4v x = sp[0], y = sp[1];
  bf8v r;
  r[0] = (short)f2bf(x[0]); r[1] = (short)f2bf(x[1]);
  r[2] = (short)f2bf(x[2]); r[3] = (short)f2bf(x[3]);
  r[4] = (short)f2bf(y[0]); r[5] = (short)f2bf(y[1]);
  r[6] = (short)f2bf(y[2]); r[7] = (short)f2bf(y[3]);
  *(bf8v*)(dst + i) = r;
}

// ---------------- 128x128x(BK=32) bf16 GEMM body (m97 structure) ----------------
// A: (4096,1024) bf16 row-major.  W: (1024,1024) bf16 row-major (n,k) = B^T input.
// OMODE 0: out bf16 (B,H,S,64); rows of A are (s*2+b).
// OMODE 1: out bf16 (B,H,64,S) [V pre-transposed]; rows of A are (s*2+b).
// OMODE 2: out fp32 (S,B,D); rows of A are (b*2048+s).
template <int OMODE>
__device__ __forceinline__ void gemm_body(
    unsigned short* Al, unsigned short* Bl,
    const unsigned short* __restrict__ A, const unsigned short* __restrict__ W,
    const float* __restrict__ bias, void* __restrict__ out) {
  const int tid = threadIdx.x;
  const int w = tid >> 6, l = tid & 63;
  const int lr = l >> 4, lc = l & 15;
  const int m0 = blockIdx.x * 128, n0 = blockIdx.y * 128;
  const int wr = w >> 1, wc = w & 1;

  f4v acc[4][4];
#pragma unroll
  for (int i = 0; i < 4; i++)
#pragma unroll
    for (int j = 0; j < 4; j++) acc[i][j] = (f4v)(0.0f);

  const int NK = 32;
  // prologue: stage kk=0 into buffer 0 (8 chunks of 1KB each for A and B)
#pragma unroll
  for (int i = 0; i < 2; i++) {
    int chunk = w * 2 + i;
    int e = (chunk * 1024 + l * 16) >> 1;   // bf16 element in tile
    int r = e >> 5, k = e & 31;
    gload16(A + (size_t)(m0 + r) * 1024 + k, Al + chunk * 512);
    gload16(W + (size_t)(n0 + r) * 1024 + k, Bl + chunk * 512);
  }

  for (int kk = 0; kk < NK; kk++) {
    const int cur = kk & 1;
    __syncthreads();   // drains this wave's vmcnt (staged tile ready) + protects reuse
    if (kk + 1 < NK) {
#pragma unroll
      for (int i = 0; i < 2; i++) {
        int chunk = w * 2 + i;
        int e = (chunk * 1024 + l * 16) >> 1;
        int r = e >> 5, k = (kk + 1) * 32 + (e & 31);
        gload16(A + (size_t)(m0 + r) * 1024 + k, Al + (cur ^ 1) * 4096 + chunk * 512);
        gload16(W + (size_t)(n0 + r) * 1024 + k, Bl + (cur ^ 1) * 4096 + chunk * 512);
      }
    }
    bf8v av[4], bv[4];
#pragma unroll
    for (int i = 0; i < 4; i++) {
      int row = wr * 64 + i * 16 + lc;
      av[i] = *(const bf8v*)(Al + cur * 4096 + row * 32 + lr * 8);
    }
#pragma unroll
    for (int j = 0; j < 4; j++) {
      int row = wc * 64 + j * 16 + lc;
      bv[j] = *(const bf8v*)(Bl + cur * 4096 + row * 32 + lr * 8);
    }
#pragma unroll
    for (int i = 0; i < 4; i++)
#pragma unroll
      for (int j = 0; j < 4; j++)
        acc[i][j] = __builtin_amdgcn_mfma_f32_16x16x32_bf16(av[i], bv[j], acc[i][j], 0, 0, 0);
  }

  // epilogue: bias + ReLU + layout-specific store
#pragma unroll
  for (int j = 0; j < 4; j++) {
    int n = n0 + wc * 64 + j * 16 + lc;
    float bj = bias[n];
#pragma unroll
    for (int i = 0; i < 4; i++) {
      int mb = m0 + wr * 64 + i * 16 + lr * 4;
#pragma unroll
      for (int q = 0; q < 4; q++) {
        float val = fmaxf(acc[i][j][q] + bj, 0.0f);
        int m = mb + q;
        if (OMODE == 2) {
          int s = m & 2047, b = m >> 11;       // A rows are b*2048+s
          ((float*)out)[(size_t)(s * 2 + b) * 1024 + n] = val;
        } else {
          int s = m >> 1, b = m & 1;           // A rows are s*2+b
          int h = n >> 6, d = n & 63;
          if (OMODE == 0)
            ((unsigned short*)out)[((size_t)(b * 16 + h) * 2048 + s) * 64 + d] = f2bf(val);
          else
            ((unsigned short*)out)[((size_t)(b * 16 + h) * 64 + d) * 2048 + s] = f2bf(val);
        }
      }
    }
  }
}

__global__ __launch_bounds__(256) void qkv_gemm(
    const unsigned short* __restrict__ qA, const unsigned short* __restrict__ kA,
    const unsigned short* __restrict__ vA,
    const unsigned short* __restrict__ Wq, const unsigned short* __restrict__ Wk,
    const unsigned short* __restrict__ Wv,
    const float* __restrict__ bq, const float* __restrict__ bk,
    const float* __restrict__ bv,
    unsigned short* __restrict__ Qh, unsigned short* __restrict__ Kh,
    unsigned short* __restrict__ Vt) {
  __shared__ __align__(16) unsigned short Al[2 * 4096];
  __shared__ __align__(16) unsigned short Bl[2 * 4096];
  int z = blockIdx.z;
  if (z == 0)      gemm_body<0>(Al, Bl, qA, Wq, bq, Qh);
  else if (z == 1) gemm_body<0>(Al, Bl, kA, Wk, bk, Kh);
  else             gemm_body<1>(Al, Bl, vA, Wv, bv, Vt);
}

__global__ __launch_bounds__(256) void out_gemm(
    const unsigned short* __restrict__ Y, const unsigned short* __restrict__ Wo,
    const float* __restrict__ bo, float* __restrict__ out) {
  __shared__ __align__(16) unsigned short Al[2 * 4096];
  __shared__ __align__(16) unsigned short Bl[2 * 4096];
  gemm_body<2>(Al, Bl, Y, Wo, bo, out);
}

// ---------------- flash attention ----------------
// Qh,Kh: (BH=32, S=2048, 64) bf16.  Vt: (BH, 64, S) bf16.  Y: (B,S,D) bf16.
// Grid (32 q-tiles, 32 bh), 256 threads. Wave w owns q-rows [q0+16w, q0+16w+16).
// K/V tiles (64x64) LDS-staged via global_load_lds with XOR-swizzled SOURCE
// (linear dest, swizzled read: byte ^= (row&7)<<4 — rule #21 both-sides form).
__global__ __launch_bounds__(256) void attn_kernel(
    const unsigned short* __restrict__ Qh, const unsigned short* __restrict__ Kh,
    const unsigned short* __restrict__ Vt, unsigned short* __restrict__ Y) {
  __shared__ __align__(16) unsigned short Kl[4096];
  __shared__ __align__(16) unsigned short Vl[4096];
  __shared__ __align__(16) unsigned short Pl[4][1024];
  const int tid = threadIdx.x, w = tid >> 6, l = tid & 63;
  const int lr = l >> 4, lc = l & 15;
  const int bh = blockIdx.y;
  const int q0 = blockIdx.x * 64;
  const size_t qkbase = (size_t)bh * 2048 * 64;
  const size_t vtbase = (size_t)bh * 64 * 2048;

  // Q fragments held in registers for the whole kernel
  bf8v qf[2];
  {
    int qrow = q0 + w * 16 + lc;
#pragma unroll
    for (int c = 0; c < 2; c++)
      qf[c] = *(const bf8v*)(Qh + qkbase + (size_t)qrow * 64 + c * 32 + lr * 8);
  }

  f4v oacc[4];
#pragma unroll
  for (int d = 0; d < 4; d++) oacc[d] = (f4v)(0.0f);
  float mrun[4], lrun[4];
#pragma unroll
  for (int q = 0; q < 4; q++) { mrun[q] = -3e38f; lrun[q] = 0.0f; }

  const float cs = 0.125f * 1.44269504088896341f;  // 1/sqrt(64) * log2(e)

  for (int t0 = 0; t0 < 2048; t0 += 64) {
    __syncthreads();   // all waves done reading Kl/Vl/Pl of previous tile
    // stage K and V tiles; source element pre-swizzled so swizzled reads see linear data
#pragma unroll
    for (int i = 0; i < 2; i++) {
      int chunk = i * 4 + w;
      int o = chunk * 1024 + l * 16;           // byte offset in tile
      int row = o >> 7;                        // 128B rows
      int e = (o ^ ((row & 7) << 4)) >> 1;     // swizzled source element
      gload16(Kh + qkbase + (size_t)t0 * 64 + e, Kl + chunk * 512);
      gload16(Vt + vtbase + (size_t)(e >> 6) * 2048 + t0 + (e & 63), Vl + chunk * 512);
    }
    __syncthreads();   // staged tile visible

    // ---- QK^T: scores 16x64, A=Q rows, B=K rows (B^T form) ----
    f4v sacc[4];
#pragma unroll
    for (int nt = 0; nt < 4; nt++) sacc[nt] = (f4v)(0.0f);
#pragma unroll
    for (int c = 0; c < 2; c++) {
#pragma unroll
      for (int nt = 0; nt < 4; nt++) {
        int row = nt * 16 + lc;
        int byte = (row << 7) + ((c * 32 + lr * 8) << 1);
        byte ^= (row & 7) << 4;
        bf8v kf = *(const bf8v*)((const char*)Kl + byte);
        sacc[nt] = __builtin_amdgcn_mfma_f32_16x16x32_bf16(qf[c], kf, sacc[nt], 0, 0, 0);
      }
    }

    // ---- online softmax (wave-parallel over the 16-lane column axis) ----
    float scale[4], rsum[4];
#pragma unroll
    for (int q = 0; q < 4; q++) {
      float v = fmaxf(fmaxf(sacc[0][q], sacc[1][q]), fmaxf(sacc[2][q], sacc[3][q]));
      v = fmaxf(v, __shfl_xor(v, 1));
      v = fmaxf(v, __shfl_xor(v, 2));
      v = fmaxf(v, __shfl_xor(v, 4));
      v = fmaxf(v, __shfl_xor(v, 8));
      float mnew = fmaxf(mrun[q], v * cs);
      scale[q] = exp2f(mrun[q] - mnew);
      mrun[q] = mnew;
      rsum[q] = 0.0f;
    }
#pragma unroll
    for (int nt = 0; nt < 4; nt++) {
#pragma unroll
      for (int q = 0; q < 4; q++) {
        float p = exp2f(sacc[nt][q] * cs - mrun[q]);
        rsum[q] += p;
        int row = lr * 4 + q;
        int byte = (row << 7) + ((nt * 16 + lc) << 1);
        byte ^= (row & 7) << 4;
        *(unsigned short*)((char*)&Pl[w][0] + byte) = f2bf(p);
      }
    }
#pragma unroll
    for (int q = 0; q < 4; q++) {
      float s = rsum[q];
      s += __shfl_xor(s, 1);
      s += __shfl_xor(s, 2);
      s += __shfl_xor(s, 4);
      s += __shfl_xor(s, 8);
      lrun[q] = lrun[q] * scale[q] + s;
#pragma unroll
      for (int d = 0; d < 4; d++) oacc[d][q] *= scale[q];
    }
    asm volatile("s_waitcnt lgkmcnt(0)" ::: "memory");  // P writes visible wave-wide

    // ---- PV: O += P(16x64) @ V(64x64); A=P from Pl, B=V from Vl (pre-transposed) ----
#pragma unroll
    for (int c = 0; c < 2; c++) {
      int pbyte = (lc << 7) + ((c * 32 + lr * 8) << 1);
      pbyte ^= (lc & 7) << 4;
      bf8v pf = *(const bf8v*)((const char*)&Pl[w][0] + pbyte);
#pragma unroll
      for (int dt = 0; dt < 4; dt++) {
        int drow = dt * 16 + lc;
        int vbyte = (drow << 7) + ((c * 32 + lr * 8) << 1);
        vbyte ^= (drow & 7) << 4;
        bf8v vf = *(const bf8v*)((const char*)Vl + vbyte);
        oacc[dt] = __builtin_amdgcn_mfma_f32_16x16x32_bf16(pf, vf, oacc[dt], 0, 0, 0);
      }
    }
  }

  // ---- epilogue: normalize, write Y (B,S,D) bf16 ----
  const int b = bh >> 4, h = bh & 15;
#pragma unroll
  for (int q = 0; q < 4; q++) {
    float inv = 1.0f / lrun[q];
    int s = q0 + w * 16 + lr * 4 + q;
#pragma unroll
    for (int dt = 0; dt < 4; dt++) {
      float v = oacc[dt][q] * inv;
      Y[((size_t)(b * 2048 + s) << 10) + h * 64 + dt * 16 + lc] = f2bf(v);
    }
  }
}

// ---------------- launch ----------------
extern "C" void kernel_launch(void* const* d_in, const int* in_sizes, int n_in,
                              void* d_out, int out_size, void* d_ws, size_t ws_size,
                              hipStream_t stream) {
  const float* q  = (const float*)d_in[0];
  const float* k  = (const float*)d_in[1];
  const float* v  = (const float*)d_in[2];
  const float* Wq = (const float*)d_in[3];
  const float* Wk = (const float*)d_in[4];
  const float* Wv = (const float*)d_in[5];
  const float* Wo = (const float*)d_in[6];
  const float* bq = (const float*)d_in[7];
  const float* bk = (const float*)d_in[8];
  const float* bv = (const float*)d_in[9];
  const float* bo = (const float*)d_in[10];

  const size_t NA = (size_t)4096 * 1024;  // activation elems
  const size_t NW = (size_t)1024 * 1024;  // weight elems
  unsigned short* qA  = (unsigned short*)d_ws;
  unsigned short* kA  = qA  + NA;
  unsigned short* vA  = kA  + NA;
  unsigned short* WqB = vA  + NA;
  unsigned short* WkB = WqB + NW;
  unsigned short* WvB = WkB + NW;
  unsigned short* WoB = WvB + NW;
  unsigned short* Qh  = WoB + NW;
  unsigned short* Kh  = Qh  + NA;
  unsigned short* Vt  = Kh  + NA;
  unsigned short* Y   = Vt  + NA;   // total ~67 MB of ws

  cvt_many<<<dim3(2048, 3), 256, 0, stream>>>(q, k, v, nullptr, qA, kA, vA, nullptr, (int)NA);
  cvt_many<<<dim3(512, 4), 256, 0, stream>>>(Wq, Wk, Wv, Wo, WqB, WkB, WvB, WoB, (int)NW);

  qkv_gemm<<<dim3(32, 8, 3), 256, 0, stream>>>(qA, kA, vA, WqB, WkB, WvB,
                                               bq, bk, bv, Qh, Kh, Vt);
  attn_kernel<<<dim3(32, 32), 256, 0, stream>>>(Qh, Kh, Vt, Y);
  out_gemm<<<dim3(32, 8), 256, 0, stream>>>(Y, WoB, bo, (float*)d_out);
}

// Round 2
// 137.346 us; speedup vs baseline: 1.4622x; 1.4622x over previous
//
#include <hip/hip_runtime.h>
#include <stdint.h>

typedef __attribute__((ext_vector_type(8))) short bf8v;   // 8 bf16 raw bits (4 VGPRs)
typedef __attribute__((ext_vector_type(4))) float f4v;
typedef __attribute__((ext_vector_type(16))) float f16v;
typedef __attribute__((ext_vector_type(4))) unsigned int u4v;

__device__ __forceinline__ unsigned short f2bf(float f) {
  unsigned int u = __float_as_uint(f);
  u += 0x7fffu + ((u >> 16) & 1u);   // round-to-nearest-even
  return (unsigned short)(u >> 16);
}

__device__ __forceinline__ void gload16(const void* g, void* l) {
  __builtin_amdgcn_global_load_lds(
      (__attribute__((address_space(1))) void*)reinterpret_cast<uintptr_t>(g),
      (__attribute__((address_space(3))) void*)reinterpret_cast<uintptr_t>(l),
      16, 0, 0);
}

__device__ __forceinline__ unsigned cvtpk(float lo, float hi) {
  unsigned r;
  asm("v_cvt_pk_bf16_f32 %0, %1, %2" : "=v"(r) : "v"(lo), "v"(hi));
  return r;
}

// ---------------- fp32 -> bf16 conversion (vectorized, G13) ----------------
__global__ __launch_bounds__(256) void cvt_many(
    const float* __restrict__ s0, const float* __restrict__ s1,
    const float* __restrict__ s2, const float* __restrict__ s3,
    unsigned short* __restrict__ d0, unsigned short* __restrict__ d1,
    unsigned short* __restrict__ d2, unsigned short* __restrict__ d3, int n) {
  int a = blockIdx.y;
  const float* src = (a == 0) ? s0 : (a == 1) ? s1 : (a == 2) ? s2 : s3;
  unsigned short* dst = (a == 0) ? d0 : (a == 1) ? d1 : (a == 2) ? d2 : d3;
  int i = (blockIdx.x * 256 + threadIdx.x) * 8;
  if (i >= n) return;
  const f4v* sp = (const f4v*)(src + i);
  f4v x = sp[0], y = sp[1];
  bf8v r;
  r[0] = (short)f2bf(x[0]); r[1] = (short)f2bf(x[1]);
  r[2] = (short)f2bf(x[2]); r[3] = (short)f2bf(x[3]);
  r[4] = (short)f2bf(y[0]); r[5] = (short)f2bf(y[1]);
  r[6] = (short)f2bf(y[2]); r[7] = (short)f2bf(y[3]);
  *(bf8v*)(dst + i) = r;
}

// ---------------- 128x128x(BK=32) bf16 GEMM body (m97 structure) ----------------
template <int OMODE>
__device__ __forceinline__ void gemm_body(
    unsigned short* Al, unsigned short* Bl,
    const unsigned short* __restrict__ A, const unsigned short* __restrict__ W,
    const float* __restrict__ bias, void* __restrict__ out) {
  const int tid = threadIdx.x;
  const int w = tid >> 6, l = tid & 63;
  const int lr = l >> 4, lc = l & 15;
  const int m0 = blockIdx.x * 128, n0 = blockIdx.y * 128;
  const int wr = w >> 1, wc = w & 1;

  f4v acc[4][4];
#pragma unroll
  for (int i = 0; i < 4; i++)
#pragma unroll
    for (int j = 0; j < 4; j++) acc[i][j] = (f4v)(0.0f);

  const int NK = 32;
#pragma unroll
  for (int i = 0; i < 2; i++) {
    int chunk = w * 2 + i;
    int e = (chunk * 1024 + l * 16) >> 1;
    int r = e >> 5, k = e & 31;
    gload16(A + (size_t)(m0 + r) * 1024 + k, Al + chunk * 512);
    gload16(W + (size_t)(n0 + r) * 1024 + k, Bl + chunk * 512);
  }

  for (int kk = 0; kk < NK; kk++) {
    const int cur = kk & 1;
    __syncthreads();
    if (kk + 1 < NK) {
#pragma unroll
      for (int i = 0; i < 2; i++) {
        int chunk = w * 2 + i;
        int e = (chunk * 1024 + l * 16) >> 1;
        int r = e >> 5, k = (kk + 1) * 32 + (e & 31);
        gload16(A + (size_t)(m0 + r) * 1024 + k, Al + (cur ^ 1) * 4096 + chunk * 512);
        gload16(W + (size_t)(n0 + r) * 1024 + k, Bl + (cur ^ 1) * 4096 + chunk * 512);
      }
    }
    bf8v av[4], bv[4];
#pragma unroll
    for (int i = 0; i < 4; i++) {
      int row = wr * 64 + i * 16 + lc;
      av[i] = *(const bf8v*)(Al + cur * 4096 + row * 32 + lr * 8);
    }
#pragma unroll
    for (int j = 0; j < 4; j++) {
      int row = wc * 64 + j * 16 + lc;
      bv[j] = *(const bf8v*)(Bl + cur * 4096 + row * 32 + lr * 8);
    }
#pragma unroll
    for (int i = 0; i < 4; i++)
#pragma unroll
      for (int j = 0; j < 4; j++)
        acc[i][j] = __builtin_amdgcn_mfma_f32_16x16x32_bf16(av[i], bv[j], acc[i][j], 0, 0, 0);
  }

#pragma unroll
  for (int j = 0; j < 4; j++) {
    int n = n0 + wc * 64 + j * 16 + lc;
    float bj = bias[n];
#pragma unroll
    for (int i = 0; i < 4; i++) {
      int mb = m0 + wr * 64 + i * 16 + lr * 4;
#pragma unroll
      for (int q = 0; q < 4; q++) {
        float val = fmaxf(acc[i][j][q] + bj, 0.0f);
        int m = mb + q;
        if (OMODE == 2) {
          int s = m & 2047, b = m >> 11;
          ((float*)out)[(size_t)(s * 2 + b) * 1024 + n] = val;
        } else {
          int s = m >> 1, b = m & 1;
          int h = n >> 6, d = n & 63;
          if (OMODE == 0)
            ((unsigned short*)out)[((size_t)(b * 16 + h) * 2048 + s) * 64 + d] = f2bf(val);
          else
            ((unsigned short*)out)[((size_t)(b * 16 + h) * 64 + d) * 2048 + s] = f2bf(val);
        }
      }
    }
  }
}

__global__ __launch_bounds__(256) void qkv_gemm(
    const unsigned short* __restrict__ qA, const unsigned short* __restrict__ kA,
    const unsigned short* __restrict__ vA,
    const unsigned short* __restrict__ Wq, const unsigned short* __restrict__ Wk,
    const unsigned short* __restrict__ Wv,
    const float* __restrict__ bq, const float* __restrict__ bk,
    const float* __restrict__ bv,
    unsigned short* __restrict__ Qh, unsigned short* __restrict__ Kh,
    unsigned short* __restrict__ Vt) {
  __shared__ __align__(16) unsigned short Al[2 * 4096];
  __shared__ __align__(16) unsigned short Bl[2 * 4096];
  int z = blockIdx.z;
  if (z == 0)      gemm_body<0>(Al, Bl, qA, Wq, bq, Qh);
  else if (z == 1) gemm_body<0>(Al, Bl, kA, Wk, bk, Kh);
  else             gemm_body<1>(Al, Bl, vA, Wv, bv, Vt);
}

__global__ __launch_bounds__(256) void out_gemm(
    const unsigned short* __restrict__ Y, const unsigned short* __restrict__ Wo,
    const float* __restrict__ bo, float* __restrict__ out) {
  __shared__ __align__(16) unsigned short Al[2 * 4096];
  __shared__ __align__(16) unsigned short Bl[2 * 4096];
  gemm_body<2>(Al, Bl, Y, Wo, bo, out);
}

// ---------------- flash attention, 32x32 swapped structure ----------------
// Qh,Kh: (BH=32, S=2048, 64) bf16.  Vt: (BH, 64, S) bf16.  Y: (B,S,D) bf16.
// Grid (16, 32), 128 threads (2 waves). Wave owns 64 q (2 subtiles of 32).
// Per KV-64 tile: double-buffered LDS K[64][64] / Vt[64][64], XOR-swizzled
// ((row&7)<<4), staged via global_load_lds with pre-swizzled source.
// QK^T: S^T[kv][q] = mfma(Kfrag, Qfrag) -> lane holds 16 p for q=lane&31.
// Softmax in-lane + one shfl_xor(32); P->bf16 via cvt_pk + permlane32_swap
// (T12); PV: O^T[d][q] = mfma(V^Tfrag, P^Tfrag) -> rescale is per-lane scalar.
__global__ __launch_bounds__(128, 1) void attn_kernel(
    const unsigned short* __restrict__ Qh, const unsigned short* __restrict__ Kh,
    const unsigned short* __restrict__ Vt, unsigned short* __restrict__ Y) {
  __shared__ __align__(16) unsigned short Kl[2][4096];
  __shared__ __align__(16) unsigned short Vl[2][4096];
  const int tid = threadIdx.x, w = tid >> 6, l = tid & 63;
  const int lo = l & 31, hi = l >> 5;
  const int bh = blockIdx.y;
  const int q0 = blockIdx.x * 128 + w * 64;
  const size_t qkbase = (size_t)bh * 2048 * 64;
  const size_t vtbase = (size_t)bh * 64 * 2048;
  const float cs = 0.125f * 1.44269504088896341f;  // 1/sqrt(64) * log2(e)

  // Q fragments (B-operand): lane holds Q[q0+s*32+lo][d = c*16+hi*8+j]
  bf8v qf[2][4];
#pragma unroll
  for (int s = 0; s < 2; s++)
#pragma unroll
    for (int c = 0; c < 4; c++)
      qf[s][c] = *(const bf8v*)(Qh + qkbase + (size_t)(q0 + s * 32 + lo) * 64 + c * 16 + hi * 8);

  f16v oacc[2][2];
#pragma unroll
  for (int s = 0; s < 2; s++)
#pragma unroll
    for (int dt = 0; dt < 2; dt++) oacc[s][dt] = (f16v)(0.0f);
  float mrun[2] = {-1e30f, -1e30f}, lrun[2] = {0.0f, 0.0f};

  // LDS read byte-addresses (within one buffer), swizzle (lo&7)<<4
  const int swl = (lo & 7) << 4;
  int akb[4], avb[2][2][2];
#pragma unroll
  for (int c = 0; c < 4; c++) akb[c] = lo * 128 + ((c * 32 + hi * 16) ^ swl);
#pragma unroll
  for (int dt = 0; dt < 2; dt++)
#pragma unroll
    for (int kvh = 0; kvh < 2; kvh++)
#pragma unroll
      for (int kc = 0; kc < 2; kc++)
        avb[dt][kvh][kc] = (dt * 32 + lo) * 128 + ((kvh * 64 + kc * 32 + hi * 16) ^ swl);

  // staging source elements (pre-swizzled so linear LDS dest + swizzled read match)
  int stE[4], stD[4], stKV[4];
#pragma unroll
  for (int i = 0; i < 4; i++) {
    int o = (w * 4 + i) * 1024 + l * 16;
    int row = o >> 7;
    stE[i] = (o ^ ((row & 7) << 4)) >> 1;
    stD[i] = stE[i] >> 6;
    stKV[i] = stE[i] & 63;
  }
  const char* KlB = (const char*)&Kl[0][0];
  const char* VlB = (const char*)&Vl[0][0];

  auto STAGE = [&](int buf, int t0) {
#pragma unroll
    for (int i = 0; i < 4; i++) {
      gload16(Kh + qkbase + (size_t)t0 * 64 + stE[i], (char*)&Kl[buf][0] + (w * 4 + i) * 1024);
      gload16(Vt + vtbase + (size_t)stD[i] * 2048 + t0 + stKV[i], (char*)&Vl[buf][0] + (w * 4 + i) * 1024);
    }
  };

  auto COMPUTE = [&](int bo) {
#pragma unroll
    for (int kvh = 0; kvh < 2; kvh++) {
      // K fragments (A-operand): row kv = kvh*32+lo, k = d
      bf8v kf[4];
#pragma unroll
      for (int c = 0; c < 4; c++)
        kf[c] = *(const bf8v*)(KlB + bo + kvh * 4096 + akb[c]);
      f16v sa = (f16v)(0.0f), sb = (f16v)(0.0f);
#pragma unroll
      for (int c = 0; c < 4; c++) {
        sa = __builtin_amdgcn_mfma_f32_32x32x16_bf16(kf[c], qf[0][c], sa, 0, 0, 0);
        sb = __builtin_amdgcn_mfma_f32_32x32x16_bf16(kf[c], qf[1][c], sb, 0, 0, 0);
      }
      // V^T fragments (A-operand): row d = dt*32+lo, k = kv
      bf8v vf[2][2];
#pragma unroll
      for (int dt = 0; dt < 2; dt++)
#pragma unroll
        for (int kc = 0; kc < 2; kc++)
          vf[dt][kc] = *(const bf8v*)(VlB + bo + avb[dt][kvh][kc]);

#pragma unroll
      for (int s = 0; s < 2; s++) {
        const f16v& sc16 = (s == 0) ? sa : sb;
        // row max over 16 in-lane + partner half
        float m16 = sc16[0];
#pragma unroll
        for (int r = 1; r < 16; r++) m16 = fmaxf(m16, sc16[r]);
        m16 = fmaxf(m16, __shfl_xor(m16, 32));
        float msc = m16 * cs;
        if (!__all(msc <= mrun[s] + 8.0f)) {       // T13 defer-max
          float mnew = fmaxf(mrun[s], msc);
          float scl = __builtin_amdgcn_exp2f(mrun[s] - mnew);
          lrun[s] *= scl;
#pragma unroll
          for (int dt = 0; dt < 2; dt++)
#pragma unroll
            for (int r = 0; r < 16; r++) oacc[s][dt][r] *= scl;
          mrun[s] = mnew;
        }
        float p[16];
        float rs = 0.0f;
#pragma unroll
        for (int r = 0; r < 16; r++) {
          p[r] = __builtin_amdgcn_exp2f(sc16[r] * cs - mrun[s]);
          rs += p[r];
        }
        rs += __shfl_xor(rs, 32);
        lrun[s] += rs;
        // T12: pack to bf16 + permlane32_swap -> P^T B-operand fragments
        bf8v pf[2];
#pragma unroll
        for (int kc = 0; kc < 2; kc++) {
          unsigned a0 = cvtpk(p[kc * 8 + 0], p[kc * 8 + 1]);
          unsigned a1 = cvtpk(p[kc * 8 + 2], p[kc * 8 + 3]);
          unsigned b0 = cvtpk(p[kc * 8 + 4], p[kc * 8 + 5]);
          unsigned b1 = cvtpk(p[kc * 8 + 6], p[kc * 8 + 7]);
          asm("v_permlane32_swap_b32 %0, %1" : "+v"(a0), "+v"(b0));
          asm("v_permlane32_swap_b32 %0, %1" : "+v"(a1), "+v"(b1));
          u4v pw;
          pw[0] = a0; pw[1] = a1; pw[2] = b0; pw[3] = b1;
          pf[kc] = __builtin_bit_cast(bf8v, pw);
        }
#pragma unroll
        for (int dt = 0; dt < 2; dt++)
#pragma unroll
          for (int kc = 0; kc < 2; kc++)
            oacc[s][dt] = __builtin_amdgcn_mfma_f32_32x32x16_bf16(vf[dt][kc], pf[kc], oacc[s][dt], 0, 0, 0);
      }
    }
  };

  STAGE(0, 0);
  __syncthreads();
#pragma unroll 1
  for (int t0 = 0; t0 < 2048; t0 += 128) {
    STAGE(1, t0 + 64);          // always valid: last staged tile is 1984
    COMPUTE(0);
    __syncthreads();
    if (t0 + 128 < 2048) STAGE(0, t0 + 128);
    COMPUTE(8192);
    __syncthreads();
  }

  // epilogue: normalize, write Y (B,S,D) bf16. Lane holds O^T[d][q=lo].
  const int b = bh >> 4, h = bh & 15;
#pragma unroll
  for (int s = 0; s < 2; s++) {
    float inv = 1.0f / lrun[s];
    int q = q0 + s * 32 + lo;
    size_t base = ((size_t)(b * 2048 + q) << 10) + h * 64;
#pragma unroll
    for (int dt = 0; dt < 2; dt++)
#pragma unroll
      for (int r = 0; r < 16; r++) {
        int d = dt * 32 + (r & 3) + 8 * (r >> 2) + 4 * hi;
        Y[base + d] = f2bf(oacc[s][dt][r] * inv);
      }
  }
}

// ---------------- launch ----------------
extern "C" void kernel_launch(void* const* d_in, const int* in_sizes, int n_in,
                              void* d_out, int out_size, void* d_ws, size_t ws_size,
                              hipStream_t stream) {
  const float* q  = (const float*)d_in[0];
  const float* k  = (const float*)d_in[1];
  const float* v  = (const float*)d_in[2];
  const float* Wq = (const float*)d_in[3];
  const float* Wk = (const float*)d_in[4];
  const float* Wv = (const float*)d_in[5];
  const float* Wo = (const float*)d_in[6];
  const float* bq = (const float*)d_in[7];
  const float* bk = (const float*)d_in[8];
  const float* bv = (const float*)d_in[9];
  const float* bo = (const float*)d_in[10];

  const size_t NA = (size_t)4096 * 1024;
  const size_t NW = (size_t)1024 * 1024;
  unsigned short* qA  = (unsigned short*)d_ws;
  unsigned short* kA  = qA  + NA;
  unsigned short* vA  = kA  + NA;
  unsigned short* WqB = vA  + NA;
  unsigned short* WkB = WqB + NW;
  unsigned short* WvB = WkB + NW;
  unsigned short* WoB = WvB + NW;
  unsigned short* Qh  = WoB + NW;
  unsigned short* Kh  = Qh  + NA;
  unsigned short* Vt  = Kh  + NA;
  unsigned short* Y   = Vt  + NA;

  cvt_many<<<dim3(2048, 3), 256, 0, stream>>>(q, k, v, nullptr, qA, kA, vA, nullptr, (int)NA);
  cvt_many<<<dim3(512, 4), 256, 0, stream>>>(Wq, Wk, Wv, Wo, WqB, WkB, WvB, WoB, (int)NW);

  qkv_gemm<<<dim3(32, 8, 3), 256, 0, stream>>>(qA, kA, vA, WqB, WkB, WvB,
                                               bq, bk, bv, Qh, Kh, Vt);
  attn_kernel<<<dim3(16, 32), 128, 0, stream>>>(Qh, Kh, Vt, Y);
  out_gemm<<<dim3(32, 8), 256, 0, stream>>>(Y, WoB, bo, (float*)d_out);
}